// Round 7
// baseline (422.173 us; speedup 1.0000x reference)
//
#include <hip/hip_runtime.h>
#include <hip/hip_bf16.h>
#include <cstdint>
#include <cstddef>

using bf16 = __hip_bfloat16;
typedef __attribute__((ext_vector_type(8))) short short8;
typedef __attribute__((ext_vector_type(4))) short short4v;
typedef __attribute__((ext_vector_type(4))) float f32x4;

constexpr int BB  = 2;
constexpr int SEQ = 2048;
constexpr int NH  = 16;
constexpr int HD  = 64;
constexpr int KPAD = 2112;   // 2049 keys padded to 33*64
constexpr int DM  = 1024;

static __device__ __forceinline__ bf16 f2b(float v) { return __float2bfloat16(v); }
static __device__ __forceinline__ float b2f(bf16 v) { return __bfloat162float(v); }

// async global->LDS, 16B per lane; lds base must be wave-uniform.
static __device__ __forceinline__ void gload16(const bf16* g, bf16* l) {
  __builtin_amdgcn_global_load_lds(
      (const __attribute__((address_space(1))) void*)g,
      (__attribute__((address_space(3))) void*)l, 16, 0, 0);
}

// ---------------------------------------------------------------- cast x -> bf16
__global__ __launch_bounds__(256) void cast_x_kernel(const float* __restrict__ src,
                                                     bf16* __restrict__ dst, int n4) {
  int idx = blockIdx.x * 256 + threadIdx.x;
  if (idx >= n4) return;
  float4 v = *(const float4*)(src + (size_t)idx * 4);
  bf16 o[4] = {f2b(v.x), f2b(v.y), f2b(v.z), f2b(v.w)};
  *(short4v*)(dst + (size_t)idx * 4) = *(short4v*)o;
}

// ---------------------------------------------------------------- zero f32 buffer
__global__ __launch_bounds__(256) void zero_kernel(float* __restrict__ dst, int n4) {
  int idx = blockIdx.x * 256 + threadIdx.x;
  if (idx >= n4) return;
  float4 z; z.x = 0.f; z.y = 0.f; z.z = 0.f; z.w = 0.f;
  *(float4*)(dst + (size_t)idx * 4) = z;
}

// ---------------------------------------------------------------- f32 -> bf16
__global__ __launch_bounds__(256) void cast_o_kernel(const float* __restrict__ src,
                                                     bf16* __restrict__ dst, int n4) {
  int idx = blockIdx.x * 256 + threadIdx.x;
  if (idx >= n4) return;
  float4 v = *(const float4*)(src + (size_t)idx * 4);
  bf16 o[4] = {f2b(v.x), f2b(v.y), f2b(v.z), f2b(v.w)};
  *(short4v*)(dst + (size_t)idx * 4) = *(short4v*)o;
}

// ------------------------------------------- transpose f32[K][N] -> bf16[N][ldDst]
__global__ __launch_bounds__(256) void transpose_cast_kernel(const float* __restrict__ src,
                                                             bf16* __restrict__ dst,
                                                             int colsN, int ldDst) {
  int n0 = blockIdx.x * 32, k0 = blockIdx.y * 32;
  __shared__ alignas(16) float t[32][33];
  int tid = threadIdx.x;
  {
    int r = tid >> 3, c4 = (tid & 7) * 4;
    float4 v = *(const float4*)(src + (size_t)(k0 + r) * colsN + n0 + c4);
    t[r][c4 + 0] = v.x; t[r][c4 + 1] = v.y; t[r][c4 + 2] = v.z; t[r][c4 + 3] = v.w;
  }
  __syncthreads();
  {
    int nl = tid >> 3, k4 = (tid & 7) * 4;
    bf16 o[4];
#pragma unroll
    for (int u = 0; u < 4; ++u) o[u] = f2b(t[k4 + u][nl]);
    *(short4v*)(dst + (size_t)(n0 + nl) * ldDst + k0 + k4) = *(short4v*)o;
  }
}

// --------------------------- m97-style GEMM: 128x128 tile, BK=32, global_load_lds
template <bool OUT_BF16, bool BIAS>
__global__ __launch_bounds__(256) void gemm_lds_kernel(
    const bf16* __restrict__ A, int lda,
    const bf16* __restrict__ BT, int ldb,
    void* __restrict__ Cv, int ldc,
    const float* __restrict__ bias, int K) {
  constexpr int BK = 32;
  const int tid = threadIdx.x, wave = tid >> 6, lane = tid & 63;
  const int lr = lane & 15, lq = lane >> 4;
  const int wm = wave >> 1, wn = wave & 1;
  const int m0 = blockIdx.y * 128, n0 = blockIdx.x * 128;
  const int srow = lane >> 2;            // 0..15 within 16-row chunk
  const int scol = (lane & 3) * 8;       // 0,8,16,24

  __shared__ alignas(16) bf16 ash[128 * BK];
  __shared__ alignas(16) bf16 bsh[128 * BK];

  f32x4 acc[4][4];
#pragma unroll
  for (int i = 0; i < 4; ++i)
#pragma unroll
    for (int j = 0; j < 4; ++j)
#pragma unroll
      for (int r = 0; r < 4; ++r) acc[i][j][r] = 0.f;

  const int nk = K / BK;
  for (int kt = 0; kt < nk; ++kt) {
    const int k0 = kt * BK;
#pragma unroll
    for (int c = 0; c < 2; ++c) {
      const int rbase = wave * 32 + c * 16;
      gload16(A + (size_t)(m0 + rbase + srow) * lda + k0 + scol, ash + rbase * BK);
      gload16(BT + (size_t)(n0 + rbase + srow) * ldb + k0 + scol, bsh + rbase * BK);
    }
    __syncthreads();
    short8 af[4], bfv[4];
#pragma unroll
    for (int i = 0; i < 4; ++i)
      af[i] = *(const short8*)&ash[(wm * 64 + i * 16 + lr) * BK + lq * 8];
#pragma unroll
    for (int j = 0; j < 4; ++j)
      bfv[j] = *(const short8*)&bsh[(wn * 64 + j * 16 + lr) * BK + lq * 8];
#pragma unroll
    for (int i = 0; i < 4; ++i)
#pragma unroll
      for (int j = 0; j < 4; ++j)
        acc[i][j] = __builtin_amdgcn_mfma_f32_16x16x32_bf16(af[i], bfv[j], acc[i][j], 0, 0, 0);
    __syncthreads();
  }
#pragma unroll
  for (int i = 0; i < 4; ++i) {
    int row0 = m0 + wm * 64 + i * 16 + lq * 4;
#pragma unroll
    for (int j = 0; j < 4; ++j) {
      int col = n0 + wn * 64 + j * 16 + lr;
      float bv = BIAS ? bias[col] : 0.f;
#pragma unroll
      for (int r = 0; r < 4; ++r) {
        float v = acc[i][j][r] + bv;
        if (OUT_BF16) ((bf16*)Cv)[(size_t)(row0 + r) * ldc + col] = f2b(v);
        else          ((float*)Cv)[(size_t)(row0 + r) * ldc + col] = v;
      }
    }
  }
}

// ------------------------------------------------------------- generic bf16 GEMM
template <int BM, int BN, int BK, int WM, int WN, bool OUT_BF16, bool BIAS>
__global__ __launch_bounds__(WM * WN * 64) void gemm_bt_kernel(
    const bf16* __restrict__ A, int lda,
    const bf16* __restrict__ BT, int ldb,
    void* __restrict__ Cv, int ldc,
    const float* __restrict__ bias, int K) {
  constexpr int THREADS = WM * WN * 64;
  constexpr int FM = BM / (WM * 16), FN = BN / (WN * 16);
  const int tid = threadIdx.x;
  const int wave = tid >> 6, lane = tid & 63;
  const int lr = lane & 15, lq = lane >> 4;
  const int wm = wave / WN, wn = wave % WN;
  const int m0 = blockIdx.y * BM, n0 = blockIdx.x * BN;

  __shared__ alignas(16) bf16 ash[BM][BK + 8];
  __shared__ alignas(16) bf16 bsh[BN][BK + 8];

  f32x4 acc[FM][FN];
#pragma unroll
  for (int i = 0; i < FM; ++i)
#pragma unroll
    for (int j = 0; j < FN; ++j)
#pragma unroll
      for (int r = 0; r < 4; ++r) acc[i][j][r] = 0.f;

  const int nk = K / BK;
  for (int kt = 0; kt < nk; ++kt) {
    const int k0 = kt * BK;
#pragma unroll
    for (int c = 0; c < (BM * BK / 8) / THREADS; ++c) {
      int idx = tid + c * THREADS;
      int row = idx / (BK / 8), kc = (idx % (BK / 8)) * 8;
      *(short8*)&ash[row][kc] = *(const short8*)(A + (size_t)(m0 + row) * lda + k0 + kc);
    }
#pragma unroll
    for (int c = 0; c < (BN * BK / 8) / THREADS; ++c) {
      int idx = tid + c * THREADS;
      int row = idx / (BK / 8), kc = (idx % (BK / 8)) * 8;
      *(short8*)&bsh[row][kc] = *(const short8*)(BT + (size_t)(n0 + row) * ldb + k0 + kc);
    }
    __syncthreads();
    short8 af[FM], bfv[FN];
#pragma unroll
    for (int i = 0; i < FM; ++i)
      af[i] = *(const short8*)&ash[wm * FM * 16 + i * 16 + lr][lq * 8];
#pragma unroll
    for (int j = 0; j < FN; ++j)
      bfv[j] = *(const short8*)&bsh[wn * FN * 16 + j * 16 + lr][lq * 8];
#pragma unroll
    for (int i = 0; i < FM; ++i)
#pragma unroll
      for (int j = 0; j < FN; ++j)
        acc[i][j] = __builtin_amdgcn_mfma_f32_16x16x32_bf16(af[i], bfv[j], acc[i][j], 0, 0, 0);
    __syncthreads();
  }
#pragma unroll
  for (int i = 0; i < FM; ++i) {
    int row0 = m0 + wm * FM * 16 + i * 16 + lq * 4;
#pragma unroll
    for (int j = 0; j < FN; ++j) {
      int col = n0 + wn * FN * 16 + j * 16 + lr;
      float bv = BIAS ? bias[col] : 0.f;
#pragma unroll
      for (int r = 0; r < 4; ++r) {
        float v = acc[i][j][r] + bv;
        if (OUT_BF16) ((bf16*)Cv)[(size_t)(row0 + r) * ldc + col] = f2b(v);
        else          ((float*)Cv)[(size_t)(row0 + r) * ldc + col] = v;
      }
    }
  }
}

// -------------------------------------------------- RoPE + heads + nulls builder
__global__ __launch_bounds__(256) void rope_build_kernel(
    const bf16* __restrict__ qkv, const float* __restrict__ rot,
    const float* __restrict__ nullk, const float* __restrict__ nullv,
    bf16* __restrict__ Q, bf16* __restrict__ Kt, bf16* __restrict__ Vt) {
  const int blk = blockIdx.x;
  const int ic = blk & 63;
  const int h = (blk >> 6) & 15;
  const int b = blk >> 10;
  const int i0 = ic * 32;
  const int tid = threadIdx.x;
  const int bh = b * NH + h;

  __shared__ alignas(16) bf16 sh[33][192];
  __shared__ alignas(16) float cs[33][32], sn[33][32];

  for (int c = 0; c < 4; ++c) {
    int idx = tid + c * 256;
    if (idx < 33 * 24) {
      int row = idx / 24, ch = idx % 24;
      int p = ch >> 3, cc = (ch & 7) * 8;
      int i = i0 - 1 + row;
      if (i >= 0)
        *(short8*)&sh[row][p * 64 + cc] =
            *(const short8*)(qkv + (size_t)(b * SEQ + i) * 3072 + p * 1024 + h * 64 + cc);
    }
  }
  for (int c = 0; c < 5; ++c) {
    int idx = tid + c * 256;
    if (idx < 33 * 32) {
      int row = idx >> 5, d = idx & 31;
      int i = i0 - 1 + row;
      if (i >= 0) {
        float f = rot[i * 32 + d];
        cs[row][d] = cosf(f);
        sn[row][d] = sinf(f);
      }
    }
  }
  __syncthreads();

  auto ropev = [&](int row, int off, int d) -> float {
    float v = b2f(sh[row][off + d]);
    if (d < 32) {
      float c = cs[row][d], s = sn[row][d];
      float v2 = b2f(sh[row][off + (d < 16 ? d + 16 : d - 16)]);
      return d < 16 ? v * c - v2 * s : v * c + v2 * s;
    }
    return v;
  };

  const int dA = tid & 63;
#pragma unroll
  for (int rep = 0; rep < 8; ++rep) {
    int il = rep * 4 + (tid >> 6);
    int row = il + 1;
    int i = i0 + il;
    float qv = ropev(row, 0, dA) * 0.125f;
    float kv = ropev(row, 64, dA);
    Q[((size_t)bh * SEQ + i) * HD + dA] = f2b(qv);
    Kt[((size_t)bh * KPAD + (i + 1)) * HD + dA] = f2b(kv);
  }
  {
    int d = tid >> 2;
    int g0 = (tid & 3) * 8;
    bf16 tmp[8];
#pragma unroll
    for (int u = 0; u < 8; ++u) {
      int j = i0 + g0 + u;
      if (j == 0) tmp[u] = f2b(nullv[h * 64 + d]);
      else        tmp[u] = f2b(ropev(j - i0, 128, d));
    }
    *(short8*)(Vt + ((size_t)bh * HD + d) * KPAD + i0 + g0) = *(short8*)tmp;
  }
  if (i0 == 0 && tid < 64)
    Kt[(size_t)bh * KPAD * HD + tid] = f2b(nullk[h * 64 + tid]);
  if (ic == 63 && tid < 64)
    Vt[((size_t)bh * HD + tid) * KPAD + 2048] = f2b(ropev(32, 128, tid));
}

// ---------------------------------------- pass 1: softmax denominators -> Linv f32
__global__ __launch_bounds__(256) void denom_kernel(
    const bf16* __restrict__ Q, const bf16* __restrict__ Kt, float* __restrict__ Linv) {
  const int bh = blockIdx.x;
  const int i0 = blockIdx.y * 32;
  const int tid = threadIdx.x;
  const int wave = tid >> 6, lane = tid & 63;
  const int lr = lane & 15, lq = lane >> 4;
  const bf16* Qp = Q + (size_t)bh * SEQ * HD;
  const bf16* Kp = Kt + (size_t)bh * KPAD * HD;

  short8 af[2][2];
#pragma unroll
  for (int fi = 0; fi < 2; ++fi)
#pragma unroll
    for (int ks = 0; ks < 2; ++ks)
      af[fi][ks] = *(const short8*)(Qp + (size_t)(i0 + fi * 16 + lr) * HD + ks * 32 + lq * 8);

  const int tmax = (i0 + 32) >> 6;
  float lacc[2][4];
#pragma unroll
  for (int fi = 0; fi < 2; ++fi)
#pragma unroll
    for (int r = 0; r < 4; ++r) lacc[fi][r] = 0.f;

  for (int t = wave; t <= tmax; t += 4) {
    f32x4 s[2][4];
#pragma unroll
    for (int fi = 0; fi < 2; ++fi)
#pragma unroll
      for (int fj = 0; fj < 4; ++fj)
#pragma unroll
        for (int r = 0; r < 4; ++r) s[fi][fj][r] = 0.f;
#pragma unroll
    for (int fj = 0; fj < 4; ++fj) {
      const bf16* kp = Kp + (size_t)(t * 64 + fj * 16 + lr) * HD + lq * 8;
      short8 b0 = *(const short8*)kp;
      short8 b1 = *(const short8*)(kp + 32);
#pragma unroll
      for (int fi = 0; fi < 2; ++fi) {
        s[fi][fj] = __builtin_amdgcn_mfma_f32_16x16x32_bf16(af[fi][0], b0, s[fi][fj], 0, 0, 0);
        s[fi][fj] = __builtin_amdgcn_mfma_f32_16x16x32_bf16(af[fi][1], b1, s[fi][fj], 0, 0, 0);
      }
    }
#pragma unroll
    for (int fi = 0; fi < 2; ++fi)
#pragma unroll
      for (int fj = 0; fj < 4; ++fj)
#pragma unroll
        for (int r = 0; r < 4; ++r) {
          int i = i0 + fi * 16 + lq * 4 + r;
          int j = t * 64 + fj * 16 + lr;
          if (j <= i + 1) lacc[fi][r] += __expf(s[fi][fj][r]);
        }
  }
#pragma unroll
  for (int m = 1; m <= 8; m <<= 1)
#pragma unroll
    for (int fi = 0; fi < 2; ++fi)
#pragma unroll
      for (int r = 0; r < 4; ++r) lacc[fi][r] += __shfl_xor(lacc[fi][r], m, 64);

  __shared__ alignas(16) float lsh[4][32];
  if (lr == 0) {
#pragma unroll
    for (int fi = 0; fi < 2; ++fi)
#pragma unroll
      for (int r = 0; r < 4; ++r) lsh[wave][fi * 16 + lq * 4 + r] = lacc[fi][r];
  }
  __syncthreads();
  if (tid < 32)
    Linv[(size_t)bh * SEQ + i0 + tid] =
        1.f / (lsh[0][tid] + lsh[1][tid] + lsh[2][tid] + lsh[3][tid]);
}

// ---- pass 2: fused QK^T + softmax + talking-heads mix + PV, balanced, atomic out
// 512 blocks: blockIdx.x -> (pair, b, jquarter). Block = two complementary 16-row
// i-tiles (ic, 127-ic), quarter of each tile's causal j-range. 8 waves, 2 heads/wave.
// LDS 72KB -> 2 blocks/CU (16 waves/CU).
__global__ __launch_bounds__(512) void fused2_kernel(
    const bf16* __restrict__ Q, const bf16* __restrict__ Kt, const bf16* __restrict__ Vt,
    const float* __restrict__ Linv, const float* __restrict__ thw,
    float* __restrict__ ohf) {
  const int pairIdx = blockIdx.x >> 3;          // 0..63
  const int b  = (blockIdx.x >> 2) & 1;
  const int jq = blockIdx.x & 3;
  const int tid = threadIdx.x;
  const int w = tid >> 6, lane = tid & 63;
  const int lr = lane & 15, lq = lane >> 4;

  // p_sh: [pos 0..1023][h], row stride 20 elems (40B) -> conflict-free u16 writes
  __shared__ alignas(16) bf16 p_sh[1024 * 20];  // 40 KB
  // p2:   [g 0..15][swizzled c], row stride 1024 (XOR swizzle on reads+writes)
  __shared__ alignas(16) bf16 p2[16 * 1024];    // 32 KB

  short8 zero8;
#pragma unroll
  for (int e = 0; e < 8; ++e) zero8[e] = 0;
  f32x4 fzero;
#pragma unroll
  for (int r = 0; r < 4; ++r) fzero[r] = 0.f;

  // W A-frag: lanes lq<2 hold W[g=lr][h=lq*8+e]; k>=16 zero.
  short8 wfrag = zero8;
  if (lq < 2) {
    bf16 tmp[8];
#pragma unroll
    for (int e = 0; e < 8; ++e) tmp[e] = f2b(thw[lr * 16 + lq * 8 + e]);
    wfrag = *(short8*)tmp;
  }

#pragma unroll
  for (int sel = 0; sel < 2; ++sel) {
    const int ic = sel ? 127 - pairIdx : pairIdx;
    const int i0 = ic * 16;
    const int n = ((i0 + 16) >> 6) + 1;          // # causal j-tiles
    const int t0 = (n * jq) >> 2;
    const int t1 = (n * (jq + 1)) >> 2;

    // per-wave heads: w and w+8
    short8 qf[2][2];
    float linv[2][4];
    const bf16* Vp[2];
    const bf16* Kp[2];
#pragma unroll
    for (int hh = 0; hh < 2; ++hh) {
      const int h = w + hh * 8;
      const int bh = b * NH + h;
      const bf16* Qp = Q + ((size_t)bh * SEQ + i0) * HD;
#pragma unroll
      for (int ks = 0; ks < 2; ++ks)
        qf[hh][ks] = *(const short8*)(Qp + (size_t)lr * HD + ks * 32 + lq * 8);
#pragma unroll
      for (int r = 0; r < 4; ++r)
        linv[hh][r] = Linv[(size_t)bh * SEQ + i0 + lq * 4 + r];
      Kp[hh] = Kt + (size_t)bh * KPAD * HD;
      Vp[hh] = Vt + (size_t)bh * HD * KPAD;
    }

    f32x4 oacc[2][4];
#pragma unroll
    for (int hh = 0; hh < 2; ++hh)
#pragma unroll
      for (int fn = 0; fn < 4; ++fn) oacc[hh][fn] = fzero;

    for (int t = t0; t < t1; ++t) {
      // ---- QK^T (both heads), exp, normalize, P -> p_sh[pos][h]
#pragma unroll
      for (int hh = 0; hh < 2; ++hh) {
        const int h = w + hh * 8;
        f32x4 s[4];
#pragma unroll
        for (int fj = 0; fj < 4; ++fj) s[fj] = fzero;
#pragma unroll
        for (int fj = 0; fj < 4; ++fj) {
          const bf16* kp = Kp[hh] + (size_t)(t * 64 + fj * 16 + lr) * HD + lq * 8;
          short8 b0 = *(const short8*)kp;
          short8 b1 = *(const short8*)(kp + 32);
          s[fj] = __builtin_amdgcn_mfma_f32_16x16x32_bf16(qf[hh][0], b0, s[fj], 0, 0, 0);
          s[fj] = __builtin_amdgcn_mfma_f32_16x16x32_bf16(qf[hh][1], b1, s[fj], 0, 0, 0);
        }
#pragma unroll
        for (int fj = 0; fj < 4; ++fj)
#pragma unroll
          for (int r = 0; r < 4; ++r) {
            int il = lq * 4 + r;
            int jl = fj * 16 + lr;
            int i = i0 + il, j = t * 64 + jl;
            float p = (j <= i + 1) ? __expf(s[fj][r]) * linv[hh][r] : 0.f;
            p_sh[(il * 64 + jl) * 20 + h] = f2b(p);
          }
      }
      __syncthreads();
      // ---- talking-heads mix: P'[g][c] = sum_h W[g][h] P[h][c]
#pragma unroll
      for (int q = 0; q < 8; ++q) {
        const int c = (w * 8 + q) * 16 + lr;
        short8 bfrag = zero8;
        if (lq < 2) {
          short4v lo = *(const short4v*)&p_sh[c * 20 + lq * 8];
          short4v hi = *(const short4v*)&p_sh[c * 20 + lq * 8 + 4];
#pragma unroll
          for (int e = 0; e < 4; ++e) { bfrag[e] = lo[e]; bfrag[4 + e] = hi[e]; }
        }
        f32x4 d = __builtin_amdgcn_mfma_f32_16x16x32_bf16(wfrag, bfrag, fzero, 0, 0, 0);
        const int sc = c ^ (((c >> 6) & 7) << 3);    // XOR swizzle (8-elem chunks)
#pragma unroll
        for (int r = 0; r < 4; ++r)
          p2[(lq * 4 + r) * 1024 + sc] = f2b(d[r]);
      }
      __syncthreads();
      // ---- PV: oacc[g] += P'[g] @ V[g]
#pragma unroll
      for (int hh = 0; hh < 2; ++hh) {
        const int h = w + hh * 8;
        short8 pa[2];
#pragma unroll
        for (int ks = 0; ks < 2; ++ks) {
          const int c = lr * 64 + ks * 32 + lq * 8;
          const int sc = c ^ (((c >> 6) & 7) << 3);
          pa[ks] = *(const short8*)&p2[h * 1024 + sc];
        }
#pragma unroll
        for (int fn = 0; fn < 4; ++fn) {
          const bf16* vp = Vp[hh] + (size_t)(fn * 16 + lr) * KPAD + t * 64 + lq * 8;
          short8 v0 = *(const short8*)vp;
          short8 v1 = *(const short8*)(vp + 32);
          oacc[hh][fn] = __builtin_amdgcn_mfma_f32_16x16x32_bf16(pa[0], v0, oacc[hh][fn], 0, 0, 0);
          oacc[hh][fn] = __builtin_amdgcn_mfma_f32_16x16x32_bf16(pa[1], v1, oacc[hh][fn], 0, 0, 0);
        }
      }
    }
    // ---- accumulate to global (f32 atomics; 4 blocks contribute per row)
#pragma unroll
    for (int hh = 0; hh < 2; ++hh) {
      const int h = w + hh * 8;
#pragma unroll
      for (int fn = 0; fn < 4; ++fn)
#pragma unroll
        for (int r = 0; r < 4; ++r)
          atomicAdd(ohf + (size_t)(b * SEQ + i0 + lq * 4 + r) * DM + h * 64 + fn * 16 + lr,
                    oacc[hh][fn][r]);
    }
    __syncthreads();   // p_sh/p2 reuse safety across sel iterations
  }
}

// ------------------------------------------------------------------- launcher
extern "C" void kernel_launch(void* const* d_in, const int* in_sizes, int n_in,
                              void* d_out, int out_size, void* d_ws, size_t ws_size,
                              hipStream_t stream) {
  const float* x     = (const float*)d_in[0];
  const float* rot   = (const float*)d_in[2];
  const float* nullk = (const float*)d_in[3];
  const float* nullv = (const float*)d_in[4];
  const float* thw   = (const float*)d_in[5];
  const float* wq    = (const float*)d_in[6];
  const float* wkv   = (const float*)d_in[7];
  const float* wout  = (const float*)d_in[8];
  const float* bout  = (const float*)d_in[9];
  float* out = (float*)d_out;

  char* ws = (char*)d_ws;
  size_t off = 0;
  auto alloc = [&](size_t bytes) { char* p = ws + off; off += (bytes + 255) & ~(size_t)255; return p; };
  bf16* x_bf    = (bf16*)alloc((size_t)BB * SEQ * DM * 2);        // 8.4 MB
  bf16* wqkv_t  = (bf16*)alloc((size_t)3072 * 1024 * 2);          // 6.3 MB
  bf16* wout_t  = (bf16*)alloc((size_t)1024 * 1024 * 2);          // 2.1 MB
  bf16* qkv_bf  = (bf16*)alloc((size_t)BB * SEQ * 3072 * 2);      // 25 MB
  bf16* Qb      = (bf16*)alloc((size_t)BB * NH * SEQ * HD * 2);   // 8.4 MB
  bf16* Kt      = (bf16*)alloc((size_t)BB * NH * KPAD * HD * 2);  // 8.7 MB
  bf16* Vt      = (bf16*)alloc((size_t)BB * NH * HD * KPAD * 2);  // 8.7 MB
  float* Linv   = (float*)alloc((size_t)BB * NH * SEQ * 4);       // 0.26 MB
  bf16* oh      = (bf16*)alloc((size_t)BB * SEQ * DM * 2);        // 8.4 MB
  (void)ws_size;
  // f32 output accumulator ALIASES qkv_bf (free after rope_build): 16.8 <= 25 MB
  float* ohf = (float*)qkv_bf;

  cast_x_kernel<<<(BB * SEQ * DM / 4 + 255) / 256, 256, 0, stream>>>(x, x_bf, BB * SEQ * DM / 4);
  transpose_cast_kernel<<<dim3(1024 / 32, 1024 / 32), 256, 0, stream>>>(wq, wqkv_t, 1024, 1024);
  transpose_cast_kernel<<<dim3(2048 / 32, 1024 / 32), 256, 0, stream>>>(wkv, wqkv_t + (size_t)1024 * 1024, 2048, 1024);
  transpose_cast_kernel<<<dim3(1024 / 32, 1024 / 32), 256, 0, stream>>>(wout, wout_t, 1024, 1024);

  gemm_lds_kernel<true, false>
      <<<dim3(3072 / 128, 4096 / 128), 256, 0, stream>>>(
          x_bf, 1024, wqkv_t, 1024, qkv_bf, 3072, nullptr, 1024);

  rope_build_kernel<<<BB * NH * (SEQ / 32), 256, 0, stream>>>(qkv_bf, rot, nullk, nullv, Qb, Kt, Vt);

  // qkv_bf no longer needed -> zero its head region as the f32 O accumulator
  zero_kernel<<<(BB * SEQ * DM / 4 + 255) / 256, 256, 0, stream>>>(ohf, BB * SEQ * DM / 4);

  denom_kernel<<<dim3(BB * NH, SEQ / 32), 256, 0, stream>>>(Qb, Kt, Linv);

  fused2_kernel<<<512, 512, 0, stream>>>(Qb, Kt, Vt, Linv, thw, ohf);

  cast_o_kernel<<<(BB * SEQ * DM / 4 + 255) / 256, 256, 0, stream>>>(ohf, oh, BB * SEQ * DM / 4);

  gemm_bt_kernel<128, 128, 32, 2, 2, false, true>
      <<<dim3(1024 / 128, 4096 / 128), 256, 0, stream>>>(
          oh, 1024, wout_t, 1024, out, 1024, bout, 1024);
}

// Round 8
// 399.163 us; speedup vs baseline: 1.0576x; 1.0576x over previous
//
#include <hip/hip_runtime.h>
#include <hip/hip_bf16.h>
#include <cstdint>
#include <cstddef>

using bf16 = __hip_bfloat16;
typedef __attribute__((ext_vector_type(8))) short short8;
typedef __attribute__((ext_vector_type(4))) short short4v;
typedef __attribute__((ext_vector_type(4))) float f32x4;

constexpr int BB  = 2;
constexpr int SEQ = 2048;
constexpr int NH  = 16;
constexpr int HD  = 64;
constexpr int KPAD = 2112;   // 2049 keys padded to 33*64
constexpr int DM  = 1024;

static __device__ __forceinline__ bf16 f2b(float v) { return __float2bfloat16(v); }
static __device__ __forceinline__ float b2f(bf16 v) { return __bfloat162float(v); }

// async global->LDS, 16B per lane; lds base must be wave-uniform.
static __device__ __forceinline__ void gload16(const bf16* g, bf16* l) {
  __builtin_amdgcn_global_load_lds(
      (const __attribute__((address_space(1))) void*)g,
      (__attribute__((address_space(3))) void*)l, 16, 0, 0);
}

// ---------------------------------------------------------------- cast x -> bf16
__global__ __launch_bounds__(256) void cast_x_kernel(const float* __restrict__ src,
                                                     bf16* __restrict__ dst, int n4) {
  int idx = blockIdx.x * 256 + threadIdx.x;
  if (idx >= n4) return;
  float4 v = *(const float4*)(src + (size_t)idx * 4);
  bf16 o[4] = {f2b(v.x), f2b(v.y), f2b(v.z), f2b(v.w)};
  *(short4v*)(dst + (size_t)idx * 4) = *(short4v*)o;
}

// ---------------------------------------------------------------- zero f32 buffer
__global__ __launch_bounds__(256) void zero_kernel(float* __restrict__ dst, int n4) {
  int idx = blockIdx.x * 256 + threadIdx.x;
  if (idx >= n4) return;
  float4 z; z.x = 0.f; z.y = 0.f; z.z = 0.f; z.w = 0.f;
  *(float4*)(dst + (size_t)idx * 4) = z;
}

// ---------------------------------------------------------------- f32 -> bf16
__global__ __launch_bounds__(256) void cast_o_kernel(const float* __restrict__ src,
                                                     bf16* __restrict__ dst, int n4) {
  int idx = blockIdx.x * 256 + threadIdx.x;
  if (idx >= n4) return;
  float4 v = *(const float4*)(src + (size_t)idx * 4);
  bf16 o[4] = {f2b(v.x), f2b(v.y), f2b(v.z), f2b(v.w)};
  *(short4v*)(dst + (size_t)idx * 4) = *(short4v*)o;
}

// ------------------------------------------- transpose f32[K][N] -> bf16[N][ldDst]
__global__ __launch_bounds__(256) void transpose_cast_kernel(const float* __restrict__ src,
                                                             bf16* __restrict__ dst,
                                                             int colsN, int ldDst) {
  int n0 = blockIdx.x * 32, k0 = blockIdx.y * 32;
  __shared__ alignas(16) float t[32][33];
  int tid = threadIdx.x;
  {
    int r = tid >> 3, c4 = (tid & 7) * 4;
    float4 v = *(const float4*)(src + (size_t)(k0 + r) * colsN + n0 + c4);
    t[r][c4 + 0] = v.x; t[r][c4 + 1] = v.y; t[r][c4 + 2] = v.z; t[r][c4 + 3] = v.w;
  }
  __syncthreads();
  {
    int nl = tid >> 3, k4 = (tid & 7) * 4;
    bf16 o[4];
#pragma unroll
    for (int u = 0; u < 4; ++u) o[u] = f2b(t[k4 + u][nl]);
    *(short4v*)(dst + (size_t)(n0 + nl) * ldDst + k0 + k4) = *(short4v*)o;
  }
}

// --------------------------- m97-style GEMM: 128x128 tile, BK=32, global_load_lds
template <bool OUT_BF16, bool BIAS>
__global__ __launch_bounds__(256) void gemm_lds_kernel(
    const bf16* __restrict__ A, int lda,
    const bf16* __restrict__ BT, int ldb,
    void* __restrict__ Cv, int ldc,
    const float* __restrict__ bias, int K) {
  constexpr int BK = 32;
  const int tid = threadIdx.x, wave = tid >> 6, lane = tid & 63;
  const int lr = lane & 15, lq = lane >> 4;
  const int wm = wave >> 1, wn = wave & 1;
  const int m0 = blockIdx.y * 128, n0 = blockIdx.x * 128;
  const int srow = lane >> 2;
  const int scol = (lane & 3) * 8;

  __shared__ alignas(16) bf16 ash[128 * BK];
  __shared__ alignas(16) bf16 bsh[128 * BK];

  f32x4 acc[4][4];
#pragma unroll
  for (int i = 0; i < 4; ++i)
#pragma unroll
    for (int j = 0; j < 4; ++j)
#pragma unroll
      for (int r = 0; r < 4; ++r) acc[i][j][r] = 0.f;

  const int nk = K / BK;
  for (int kt = 0; kt < nk; ++kt) {
    const int k0 = kt * BK;
#pragma unroll
    for (int c = 0; c < 2; ++c) {
      const int rbase = wave * 32 + c * 16;
      gload16(A + (size_t)(m0 + rbase + srow) * lda + k0 + scol, ash + rbase * BK);
      gload16(BT + (size_t)(n0 + rbase + srow) * ldb + k0 + scol, bsh + rbase * BK);
    }
    __syncthreads();
    short8 af[4], bfv[4];
#pragma unroll
    for (int i = 0; i < 4; ++i)
      af[i] = *(const short8*)&ash[(wm * 64 + i * 16 + lr) * BK + lq * 8];
#pragma unroll
    for (int j = 0; j < 4; ++j)
      bfv[j] = *(const short8*)&bsh[(wn * 64 + j * 16 + lr) * BK + lq * 8];
#pragma unroll
    for (int i = 0; i < 4; ++i)
#pragma unroll
      for (int j = 0; j < 4; ++j)
        acc[i][j] = __builtin_amdgcn_mfma_f32_16x16x32_bf16(af[i], bfv[j], acc[i][j], 0, 0, 0);
    __syncthreads();
  }
#pragma unroll
  for (int i = 0; i < 4; ++i) {
    int row0 = m0 + wm * 64 + i * 16 + lq * 4;
#pragma unroll
    for (int j = 0; j < 4; ++j) {
      int col = n0 + wn * 64 + j * 16 + lr;
      float bv = BIAS ? bias[col] : 0.f;
#pragma unroll
      for (int r = 0; r < 4; ++r) {
        float v = acc[i][j][r] + bv;
        if (OUT_BF16) ((bf16*)Cv)[(size_t)(row0 + r) * ldc + col] = f2b(v);
        else          ((float*)Cv)[(size_t)(row0 + r) * ldc + col] = v;
      }
    }
  }
}

// -------------------------------------------------- RoPE + heads + nulls builder
__global__ __launch_bounds__(256) void rope_build_kernel(
    const bf16* __restrict__ qkv, const float* __restrict__ rot,
    const float* __restrict__ nullk, const float* __restrict__ nullv,
    bf16* __restrict__ Q, bf16* __restrict__ Kt, bf16* __restrict__ Vt) {
  const int blk = blockIdx.x;
  const int ic = blk & 63;
  const int h = (blk >> 6) & 15;
  const int b = blk >> 10;
  const int i0 = ic * 32;
  const int tid = threadIdx.x;
  const int bh = b * NH + h;

  __shared__ alignas(16) bf16 sh[33][192];
  __shared__ alignas(16) float cs[33][32], sn[33][32];

  for (int c = 0; c < 4; ++c) {
    int idx = tid + c * 256;
    if (idx < 33 * 24) {
      int row = idx / 24, ch = idx % 24;
      int p = ch >> 3, cc = (ch & 7) * 8;
      int i = i0 - 1 + row;
      if (i >= 0)
        *(short8*)&sh[row][p * 64 + cc] =
            *(const short8*)(qkv + (size_t)(b * SEQ + i) * 3072 + p * 1024 + h * 64 + cc);
    }
  }
  for (int c = 0; c < 5; ++c) {
    int idx = tid + c * 256;
    if (idx < 33 * 32) {
      int row = idx >> 5, d = idx & 31;
      int i = i0 - 1 + row;
      if (i >= 0) {
        float f = rot[i * 32 + d];
        cs[row][d] = cosf(f);
        sn[row][d] = sinf(f);
      }
    }
  }
  __syncthreads();

  auto ropev = [&](int row, int off, int d) -> float {
    float v = b2f(sh[row][off + d]);
    if (d < 32) {
      float c = cs[row][d], s = sn[row][d];
      float v2 = b2f(sh[row][off + (d < 16 ? d + 16 : d - 16)]);
      return d < 16 ? v * c - v2 * s : v * c + v2 * s;
    }
    return v;
  };

  const int dA = tid & 63;
#pragma unroll
  for (int rep = 0; rep < 8; ++rep) {
    int il = rep * 4 + (tid >> 6);
    int row = il + 1;
    int i = i0 + il;
    float qv = ropev(row, 0, dA) * 0.125f;
    float kv = ropev(row, 64, dA);
    Q[((size_t)bh * SEQ + i) * HD + dA] = f2b(qv);
    Kt[((size_t)bh * KPAD + (i + 1)) * HD + dA] = f2b(kv);
  }
  {
    int d = tid >> 2;
    int g0 = (tid & 3) * 8;
    bf16 tmp[8];
#pragma unroll
    for (int u = 0; u < 8; ++u) {
      int j = i0 + g0 + u;
      if (j == 0) tmp[u] = f2b(nullv[h * 64 + d]);
      else        tmp[u] = f2b(ropev(j - i0, 128, d));
    }
    *(short8*)(Vt + ((size_t)bh * HD + d) * KPAD + i0 + g0) = *(short8*)tmp;
  }
  if (i0 == 0 && tid < 64)
    Kt[(size_t)bh * KPAD * HD + tid] = f2b(nullk[h * 64 + tid]);
  if (ic == 63 && tid < 64)
    Vt[((size_t)bh * HD + tid) * KPAD + 2048] = f2b(ropev(32, 128, tid));
}

// ---------------------------------------- pass 1: softmax denominators -> Linv f32
__global__ __launch_bounds__(256) void denom_kernel(
    const bf16* __restrict__ Q, const bf16* __restrict__ Kt, float* __restrict__ Linv) {
  const int bh = blockIdx.x;
  const int i0 = blockIdx.y * 32;
  const int tid = threadIdx.x;
  const int wave = tid >> 6, lane = tid & 63;
  const int lr = lane & 15, lq = lane >> 4;
  const bf16* Qp = Q + (size_t)bh * SEQ * HD;
  const bf16* Kp = Kt + (size_t)bh * KPAD * HD;

  short8 af[2][2];
#pragma unroll
  for (int fi = 0; fi < 2; ++fi)
#pragma unroll
    for (int ks = 0; ks < 2; ++ks)
      af[fi][ks] = *(const short8*)(Qp + (size_t)(i0 + fi * 16 + lr) * HD + ks * 32 + lq * 8);

  const int tmax = (i0 + 32) >> 6;
  float lacc[2][4];
#pragma unroll
  for (int fi = 0; fi < 2; ++fi)
#pragma unroll
    for (int r = 0; r < 4; ++r) lacc[fi][r] = 0.f;

  for (int t = wave; t <= tmax; t += 4) {
    f32x4 s[2][4];
#pragma unroll
    for (int fi = 0; fi < 2; ++fi)
#pragma unroll
      for (int fj = 0; fj < 4; ++fj)
#pragma unroll
        for (int r = 0; r < 4; ++r) s[fi][fj][r] = 0.f;
#pragma unroll
    for (int fj = 0; fj < 4; ++fj) {
      const bf16* kp = Kp + (size_t)(t * 64 + fj * 16 + lr) * HD + lq * 8;
      short8 b0 = *(const short8*)kp;
      short8 b1 = *(const short8*)(kp + 32);
#pragma unroll
      for (int fi = 0; fi < 2; ++fi) {
        s[fi][fj] = __builtin_amdgcn_mfma_f32_16x16x32_bf16(af[fi][0], b0, s[fi][fj], 0, 0, 0);
        s[fi][fj] = __builtin_amdgcn_mfma_f32_16x16x32_bf16(af[fi][1], b1, s[fi][fj], 0, 0, 0);
      }
    }
#pragma unroll
    for (int fi = 0; fi < 2; ++fi)
#pragma unroll
      for (int fj = 0; fj < 4; ++fj)
#pragma unroll
        for (int r = 0; r < 4; ++r) {
          int i = i0 + fi * 16 + lq * 4 + r;
          int j = t * 64 + fj * 16 + lr;
          if (j <= i + 1) lacc[fi][r] += __expf(s[fi][fj][r]);
        }
  }
#pragma unroll
  for (int m = 1; m <= 8; m <<= 1)
#pragma unroll
    for (int fi = 0; fi < 2; ++fi)
#pragma unroll
      for (int r = 0; r < 4; ++r) lacc[fi][r] += __shfl_xor(lacc[fi][r], m, 64);

  __shared__ alignas(16) float lsh[4][32];
  if (lr == 0) {
#pragma unroll
    for (int fi = 0; fi < 2; ++fi)
#pragma unroll
      for (int r = 0; r < 4; ++r) lsh[wave][fi * 16 + lq * 4 + r] = lacc[fi][r];
  }
  __syncthreads();
  if (tid < 32)
    Linv[(size_t)bh * SEQ + i0 + tid] =
        1.f / (lsh[0][tid] + lsh[1][tid] + lsh[2][tid] + lsh[3][tid]);
}

// ---- Path A 2a: per-b QK^T + softmax + talking-heads mix -> Pm[g][i][j] (bf16)
// grid (33 j-tiles, 64 i-tiles); 256 thr, 4 waves x 4 heads. Zero-fills the
// band (tmax, (ic>>1)+1] so pv64's 32-aligned K-loop reads only written data.
__global__ __launch_bounds__(256) void pmix_kernel(
    const bf16* __restrict__ Q, const bf16* __restrict__ Kt,
    const float* __restrict__ Linv, const float* __restrict__ thw,
    bf16* __restrict__ Pm) {
  const int t = blockIdx.x;
  const int ic = blockIdx.y;
  const int i0 = ic * 32;
  const int tid = threadIdx.x, wave = tid >> 6, lane = tid & 63;
  const int lr = lane & 15, lq = lane >> 4;
  const int tmax = (i0 + 32) >> 6;

  short8 zero8;
#pragma unroll
  for (int e = 0; e < 8; ++e) zero8[e] = 0;

  if (t > tmax) {                                  // zero-fill band or skip
    if (t > (ic >> 1) + 1) return;
#pragma unroll
    for (int k = 0; k < 16; ++k) {
      int idx = tid + k * 256;
      int g = idx >> 8, rest = idx & 255;
      int il = rest >> 3, jc = (rest & 7) * 8;
      *(short8*)(Pm + ((size_t)g * SEQ + i0 + il) * KPAD + t * 64 + jc) = zero8;
    }
    return;
  }

  __shared__ alignas(16) bf16 p_sh[2048][16];      // [il*64+jl][h]  64 KB

  f32x4 fzero;
#pragma unroll
  for (int r = 0; r < 4; ++r) fzero[r] = 0.f;

  short8 wfrag = zero8;                            // W[g=lr][h=lq*8+e], k>=16 zero
  if (lq < 2) {
    bf16 tmp[8];
#pragma unroll
    for (int e = 0; e < 8; ++e) tmp[e] = f2b(thw[lr * 16 + lq * 8 + e]);
    wfrag = *(short8*)tmp;
  }

#pragma unroll
  for (int hh = 0; hh < 4; ++hh) {
    const int h = wave * 4 + hh;
    const bf16* Qp = Q + ((size_t)h * SEQ + i0) * HD;
    const bf16* Kp = Kt + ((size_t)h * KPAD + t * 64) * HD;
    short8 qf[2][2];
#pragma unroll
    for (int fi = 0; fi < 2; ++fi)
#pragma unroll
      for (int ks = 0; ks < 2; ++ks)
        qf[fi][ks] = *(const short8*)(Qp + (size_t)(fi * 16 + lr) * HD + ks * 32 + lq * 8);
    float linv[2][4];
#pragma unroll
    for (int fi = 0; fi < 2; ++fi)
#pragma unroll
      for (int r = 0; r < 4; ++r)
        linv[fi][r] = Linv[(size_t)h * SEQ + i0 + fi * 16 + lq * 4 + r];

    f32x4 s[2][4];
#pragma unroll
    for (int fi = 0; fi < 2; ++fi)
#pragma unroll
      for (int fj = 0; fj < 4; ++fj) s[fi][fj] = fzero;
#pragma unroll
    for (int fj = 0; fj < 4; ++fj) {
      const bf16* kp = Kp + (size_t)(fj * 16 + lr) * HD + lq * 8;
      short8 b0 = *(const short8*)kp;
      short8 b1 = *(const short8*)(kp + 32);
#pragma unroll
      for (int fi = 0; fi < 2; ++fi) {
        s[fi][fj] = __builtin_amdgcn_mfma_f32_16x16x32_bf16(qf[fi][0], b0, s[fi][fj], 0, 0, 0);
        s[fi][fj] = __builtin_amdgcn_mfma_f32_16x16x32_bf16(qf[fi][1], b1, s[fi][fj], 0, 0, 0);
      }
    }
#pragma unroll
    for (int fi = 0; fi < 2; ++fi)
#pragma unroll
      for (int fj = 0; fj < 4; ++fj)
#pragma unroll
        for (int r = 0; r < 4; ++r) {
          int il = fi * 16 + lq * 4 + r;
          int jl = fj * 16 + lr;
          int i = i0 + il, j = t * 64 + jl;
          float p = (j <= i + 1) ? __expf(s[fi][fj][r]) * linv[fi][r] : 0.f;
          p_sh[il * 64 + jl][h] = f2b(p);
        }
  }
  __syncthreads();

  // mix via MFMA: P'[g][c] = sum_h W[g][h] P[h][c]; write direct to global.
#pragma unroll
  for (int q = 0; q < 32; ++q) {
    const int c = (wave * 32 + q) * 16 + lr;
    short8 bfrag = zero8;
    if (lq < 2) bfrag = *(const short8*)&p_sh[c][lq * 8];
    f32x4 d = __builtin_amdgcn_mfma_f32_16x16x32_bf16(wfrag, bfrag, fzero, 0, 0, 0);
    const int il = c >> 6, jl = c & 63;
#pragma unroll
    for (int r = 0; r < 4; ++r) {
      const int g = lq * 4 + r;
      Pm[((size_t)g * SEQ + i0 + il) * KPAD + t * 64 + jl] = f2b(d[r]);
    }
  }
}

// ---- Path A 2b: per-b oh[i, g*64+d] = sum_j Pm[g,i,j] * Vt[g,d,j], K-lim m0+65
__global__ __launch_bounds__(256) void pv64_kernel(
    const bf16* __restrict__ Pm, const bf16* __restrict__ Vt, bf16* __restrict__ oh) {
  const int g = blockIdx.x;
  const int m0 = blockIdx.y * 64;
  const int tid = threadIdx.x, w = tid >> 6, lane = tid & 63;
  const int lr = lane & 15, lq = lane >> 4;
  const bf16* A  = Pm + (size_t)g * SEQ * KPAD;
  const bf16* BT = Vt + (size_t)g * HD * KPAD;

  __shared__ alignas(16) bf16 ash[64][40];
  __shared__ alignas(16) bf16 bsh[64][40];

  f32x4 acc[4];
#pragma unroll
  for (int j = 0; j < 4; ++j)
#pragma unroll
    for (int r = 0; r < 4; ++r) acc[j][r] = 0.f;

  const int nk = m0 / 32 + 3;                       // covers K = m0 + 96 > m0+65
  for (int kt = 0; kt < nk; ++kt) {
    const int k0 = kt * 32;
    *(short8*)&ash[tid >> 2][(tid & 3) * 8] =
        *(const short8*)(A + (size_t)(m0 + (tid >> 2)) * KPAD + k0 + (tid & 3) * 8);
    *(short8*)&bsh[tid >> 2][(tid & 3) * 8] =
        *(const short8*)(BT + (size_t)(tid >> 2) * KPAD + k0 + (tid & 3) * 8);
    __syncthreads();
    short8 af = *(const short8*)&ash[w * 16 + lr][lq * 8];
#pragma unroll
    for (int j = 0; j < 4; ++j) {
      short8 bfv = *(const short8*)&bsh[j * 16 + lr][lq * 8];
      acc[j] = __builtin_amdgcn_mfma_f32_16x16x32_bf16(af, bfv, acc[j], 0, 0, 0);
    }
    __syncthreads();
  }
#pragma unroll
  for (int j = 0; j < 4; ++j)
#pragma unroll
    for (int r = 0; r < 4; ++r)
      oh[(size_t)(m0 + w * 16 + lq * 4 + r) * DM + g * 64 + j * 16 + lr] = f2b(acc[j][r]);
}

// ---- Path B fallback: r6 fused2 (measured 181us) --------------------------------
__global__ __launch_bounds__(512) void fused2_kernel(
    const bf16* __restrict__ Q, const bf16* __restrict__ Kt, const bf16* __restrict__ Vt,
    const float* __restrict__ Linv, const float* __restrict__ thw,
    float* __restrict__ ohf) {
  const int pairIdx = blockIdx.x >> 2;
  const int b  = (blockIdx.x >> 1) & 1;
  const int jh = blockIdx.x & 1;
  const int tid = threadIdx.x;
  const int w = tid >> 6, lane = tid & 63;
  const int lr = lane & 15, lq = lane >> 4;

  __shared__ alignas(16) bf16 p_sh[1024 * 24];
  __shared__ alignas(16) bf16 p2[16 * 1032];

  short8 zero8;
#pragma unroll
  for (int e = 0; e < 8; ++e) zero8[e] = 0;
  f32x4 fzero;
#pragma unroll
  for (int r = 0; r < 4; ++r) fzero[r] = 0.f;

  short8 wfrag = zero8;
  if (lq < 2) {
    bf16 tmp[8];
#pragma unroll
    for (int e = 0; e < 8; ++e) tmp[e] = f2b(thw[lr * 16 + lq * 8 + e]);
    wfrag = *(short8*)tmp;
  }

#pragma unroll
  for (int sel = 0; sel < 2; ++sel) {
    const int ic = sel ? 127 - pairIdx : pairIdx;
    const int i0 = ic * 16;
    const int n = ((i0 + 16) >> 6) + 1;
    const int half = (n + 1) >> 1;
    const int t0 = jh ? half : 0;
    const int t1 = jh ? n : half;

    short8 qf[2][2];
    float linv[2][4];
    const bf16* Vp[2];
    const bf16* Kp[2];
#pragma unroll
    for (int hh = 0; hh < 2; ++hh) {
      const int h = w + hh * 8;
      const int bh = b * NH + h;
      const bf16* Qp = Q + ((size_t)bh * SEQ + i0) * HD;
#pragma unroll
      for (int ks = 0; ks < 2; ++ks)
        qf[hh][ks] = *(const short8*)(Qp + (size_t)lr * HD + ks * 32 + lq * 8);
#pragma unroll
      for (int r = 0; r < 4; ++r)
        linv[hh][r] = Linv[(size_t)bh * SEQ + i0 + lq * 4 + r];
      Kp[hh] = Kt + (size_t)bh * KPAD * HD;
      Vp[hh] = Vt + (size_t)bh * HD * KPAD;
    }

    f32x4 oacc[2][4];
#pragma unroll
    for (int hh = 0; hh < 2; ++hh)
#pragma unroll
      for (int fn = 0; fn < 4; ++fn) oacc[hh][fn] = fzero;

    for (int t = t0; t < t1; ++t) {
#pragma unroll
      for (int hh = 0; hh < 2; ++hh) {
        const int h = w + hh * 8;
        f32x4 s[4];
#pragma unroll
        for (int fj = 0; fj < 4; ++fj) s[fj] = fzero;
#pragma unroll
        for (int fj = 0; fj < 4; ++fj) {
          const bf16* kp = Kp[hh] + (size_t)(t * 64 + fj * 16 + lr) * HD + lq * 8;
          short8 b0 = *(const short8*)kp;
          short8 b1 = *(const short8*)(kp + 32);
          s[fj] = __builtin_amdgcn_mfma_f32_16x16x32_bf16(qf[hh][0], b0, s[fj], 0, 0, 0);
          s[fj] = __builtin_amdgcn_mfma_f32_16x16x32_bf16(qf[hh][1], b1, s[fj], 0, 0, 0);
        }
#pragma unroll
        for (int fj = 0; fj < 4; ++fj)
#pragma unroll
          for (int r = 0; r < 4; ++r) {
            int il = lq * 4 + r;
            int jl = fj * 16 + lr;
            int i = i0 + il, j = t * 64 + jl;
            float p = (j <= i + 1) ? __expf(s[fj][r]) * linv[hh][r] : 0.f;
            p_sh[(il * 64 + jl) * 24 + h] = f2b(p);
          }
      }
      __syncthreads();
#pragma unroll
      for (int q = 0; q < 8; ++q) {
        const int c = (w * 8 + q) * 16 + lr;
        short8 bfrag = zero8;
        if (lq < 2) bfrag = *(const short8*)&p_sh[c * 24 + lq * 8];
        f32x4 d = __builtin_amdgcn_mfma_f32_16x16x32_bf16(wfrag, bfrag, fzero, 0, 0, 0);
        const int sc = c ^ (((c >> 6) & 7) << 3);
#pragma unroll
        for (int r = 0; r < 4; ++r)
          p2[(lq * 4 + r) * 1032 + sc] = f2b(d[r]);
      }
      __syncthreads();
#pragma unroll
      for (int hh = 0; hh < 2; ++hh) {
        const int h = w + hh * 8;
        short8 pa[2];
#pragma unroll
        for (int ks = 0; ks < 2; ++ks) {
          const int c = lr * 64 + ks * 32 + lq * 8;
          const int sc = c ^ (((c >> 6) & 7) << 3);
          pa[ks] = *(const short8*)&p2[h * 1032 + sc];
        }
#pragma unroll
        for (int fn = 0; fn < 4; ++fn) {
          const bf16* vp = Vp[hh] + (size_t)(fn * 16 + lr) * KPAD + t * 64 + lq * 8;
          short8 v0 = *(const short8*)vp;
          short8 v1 = *(const short8*)(vp + 32);
          oacc[hh][fn] = __builtin_amdgcn_mfma_f32_16x16x32_bf16(pa[0], v0, oacc[hh][fn], 0, 0, 0);
          oacc[hh][fn] = __builtin_amdgcn_mfma_f32_16x16x32_bf16(pa[1], v1, oacc[hh][fn], 0, 0, 0);
        }
      }
    }
#pragma unroll
    for (int hh = 0; hh < 2; ++hh) {
      const int h = w + hh * 8;
#pragma unroll
      for (int fn = 0; fn < 4; ++fn)
#pragma unroll
        for (int r = 0; r < 4; ++r)
          atomicAdd(ohf + (size_t)(b * SEQ + i0 + lq * 4 + r) * DM + h * 64 + fn * 16 + lr,
                    oacc[hh][fn][r]);
    }
    __syncthreads();
  }
}

// ------------------------------------------------------------------- launcher
extern "C" void kernel_launch(void* const* d_in, const int* in_sizes, int n_in,
                              void* d_out, int out_size, void* d_ws, size_t ws_size,
                              hipStream_t stream) {
  const float* x     = (const float*)d_in[0];
  const float* rot   = (const float*)d_in[2];
  const float* nullk = (const float*)d_in[3];
  const float* nullv = (const float*)d_in[4];
  const float* thw   = (const float*)d_in[5];
  const float* wq    = (const float*)d_in[6];
  const float* wkv   = (const float*)d_in[7];
  const float* wout  = (const float*)d_in[8];
  const float* bout  = (const float*)d_in[9];
  float* out = (float*)d_out;

  char* ws = (char*)d_ws;
  size_t off = 0;
  auto alloc = [&](size_t bytes) { char* p = ws + off; off += (bytes + 255) & ~(size_t)255; return p; };
  bf16* x_bf    = (bf16*)alloc((size_t)BB * SEQ * DM * 2);        // 8.4 MB
  bf16* wqkv_t  = (bf16*)alloc((size_t)3072 * 1024 * 2);          // 6.3 MB
  bf16* wout_t  = (bf16*)alloc((size_t)1024 * 1024 * 2);          // 2.1 MB
  bf16* Qb      = (bf16*)alloc((size_t)BB * NH * SEQ * HD * 2);   // 8.4 MB
  bf16* Kt      = (bf16*)alloc((size_t)BB * NH * KPAD * HD * 2);  // 8.7 MB
  bf16* Vt      = (bf16*)alloc((size_t)BB * NH * HD * KPAD * 2);  // 8.7 MB
  float* Linv   = (float*)alloc((size_t)BB * NH * SEQ * 4);       // 0.26 MB
  bf16* oh      = (bf16*)alloc((size_t)BB * SEQ * DM * 2);        // 8.4 MB
  // shared region: qkv_bf (25.2 MB, dead after rope) overlapped with Pm (138.4 MB)
  const size_t shared_off = off;
  bf16* qkv_bf = (bf16*)(ws + shared_off);
  bf16* Pm     = (bf16*)(ws + shared_off);
  const size_t PM_BYTES = (size_t)NH * SEQ * KPAD * 2;            // per-b: 138.4 MB
  const bool pathA = (shared_off + PM_BYTES) <= ws_size;          // needs ~189.6 MB
  float* ohf = (float*)qkv_bf;                                    // Path B accumulator

  cast_x_kernel<<<(BB * SEQ * DM / 4 + 255) / 256, 256, 0, stream>>>(x, x_bf, BB * SEQ * DM / 4);
  transpose_cast_kernel<<<dim3(1024 / 32, 1024 / 32), 256, 0, stream>>>(wq, wqkv_t, 1024, 1024);
  transpose_cast_kernel<<<dim3(2048 / 32, 1024 / 32), 256, 0, stream>>>(wkv, wqkv_t + (size_t)1024 * 1024, 2048, 1024);
  transpose_cast_kernel<<<dim3(1024 / 32, 1024 / 32), 256, 0, stream>>>(wout, wout_t, 1024, 1024);

  gemm_lds_kernel<true, false>
      <<<dim3(3072 / 128, 4096 / 128), 256, 0, stream>>>(
          x_bf, 1024, wqkv_t, 1024, qkv_bf, 3072, nullptr, 1024);

  rope_build_kernel<<<BB * NH * (SEQ / 32), 256, 0, stream>>>(qkv_bf, rot, nullk, nullv, Qb, Kt, Vt);

  denom_kernel<<<dim3(BB * NH, SEQ / 32), 256, 0, stream>>>(Qb, Kt, Linv);

  if (pathA) {
    for (int b = 0; b < BB; ++b) {
      pmix_kernel<<<dim3(33, 64), 256, 0, stream>>>(
          Qb + (size_t)b * NH * SEQ * HD,
          Kt + (size_t)b * NH * KPAD * HD,
          Linv + (size_t)b * NH * SEQ, thw, Pm);
      pv64_kernel<<<dim3(16, 32), 256, 0, stream>>>(
          Pm, Vt + (size_t)b * NH * HD * KPAD, oh + (size_t)b * SEQ * DM);
    }
  } else {
    zero_kernel<<<(BB * SEQ * DM / 4 + 255) / 256, 256, 0, stream>>>(ohf, BB * SEQ * DM / 4);
    fused2_kernel<<<256, 512, 0, stream>>>(Qb, Kt, Vt, Linv, thw, ohf);
    cast_o_kernel<<<(BB * SEQ * DM / 4 + 255) / 256, 256, 0, stream>>>(ohf, oh, BB * SEQ * DM / 4);
  }

  gemm_lds_kernel<false, true>
      <<<dim3(1024 / 128, 4096 / 128), 256, 0, stream>>>(
          oh, 1024, wout_t, 1024, out, 1024, bout, 1024);
}

// Round 9
// 379.921 us; speedup vs baseline: 1.1112x; 1.0506x over previous
//
#include <hip/hip_runtime.h>
#include <hip/hip_bf16.h>
#include <cstdint>
#include <cstddef>

using bf16 = __hip_bfloat16;
typedef __attribute__((ext_vector_type(8))) short short8;
typedef __attribute__((ext_vector_type(4))) short short4v;
typedef __attribute__((ext_vector_type(4))) float f32x4;

constexpr int BB  = 2;
constexpr int SEQ = 2048;
constexpr int NH  = 16;
constexpr int HD  = 64;
constexpr int KPAD = 2112;   // 2049 keys padded to 33*64
constexpr int DM  = 1024;

static __device__ __forceinline__ bf16 f2b(float v) { return __float2bfloat16(v); }
static __device__ __forceinline__ float b2f(bf16 v) { return __bfloat162float(v); }

// async global->LDS, 16B per lane; lds base must be wave-uniform.
static __device__ __forceinline__ void gload16(const bf16* g, bf16* l) {
  __builtin_amdgcn_global_load_lds(
      (const __attribute__((address_space(1))) void*)g,
      (__attribute__((address_space(3))) void*)l, 16, 0, 0);
}

// ---------------------------------------------------------------- cast x -> bf16
__global__ __launch_bounds__(256) void cast_x_kernel(const float* __restrict__ src,
                                                     bf16* __restrict__ dst, int n4) {
  int idx = blockIdx.x * 256 + threadIdx.x;
  if (idx >= n4) return;
  float4 v = *(const float4*)(src + (size_t)idx * 4);
  bf16 o[4] = {f2b(v.x), f2b(v.y), f2b(v.z), f2b(v.w)};
  *(short4v*)(dst + (size_t)idx * 4) = *(short4v*)o;
}

// ---------------------------------------------------------------- zero f32 buffer
__global__ __launch_bounds__(256) void zero_kernel(float* __restrict__ dst, int n4) {
  int idx = blockIdx.x * 256 + threadIdx.x;
  if (idx >= n4) return;
  float4 z; z.x = 0.f; z.y = 0.f; z.z = 0.f; z.w = 0.f;
  *(float4*)(dst + (size_t)idx * 4) = z;
}

// ---------------------------------------------------------------- f32 -> bf16
__global__ __launch_bounds__(256) void cast_o_kernel(const float* __restrict__ src,
                                                     bf16* __restrict__ dst, int n4) {
  int idx = blockIdx.x * 256 + threadIdx.x;
  if (idx >= n4) return;
  float4 v = *(const float4*)(src + (size_t)idx * 4);
  bf16 o[4] = {f2b(v.x), f2b(v.y), f2b(v.z), f2b(v.w)};
  *(short4v*)(dst + (size_t)idx * 4) = *(short4v*)o;
}

// ------------------------------------------- transpose f32[K][N] -> bf16[N][ldDst]
__global__ __launch_bounds__(256) void transpose_cast_kernel(const float* __restrict__ src,
                                                             bf16* __restrict__ dst,
                                                             int colsN, int ldDst) {
  int n0 = blockIdx.x * 32, k0 = blockIdx.y * 32;
  __shared__ alignas(16) float t[32][33];
  int tid = threadIdx.x;
  {
    int r = tid >> 3, c4 = (tid & 7) * 4;
    float4 v = *(const float4*)(src + (size_t)(k0 + r) * colsN + n0 + c4);
    t[r][c4 + 0] = v.x; t[r][c4 + 1] = v.y; t[r][c4 + 2] = v.z; t[r][c4 + 3] = v.w;
  }
  __syncthreads();
  {
    int nl = tid >> 3, k4 = (tid & 7) * 4;
    bf16 o[4];
#pragma unroll
    for (int u = 0; u < 4; ++u) o[u] = f2b(t[k4 + u][nl]);
    *(short4v*)(dst + (size_t)(n0 + nl) * ldDst + k0 + k4) = *(short4v*)o;
  }
}

// --------------------------- m97-style GEMM: 128x128 tile, BK=32, global_load_lds
template <bool OUT_BF16, bool BIAS>
__global__ __launch_bounds__(256) void gemm_lds_kernel(
    const bf16* __restrict__ A, int lda,
    const bf16* __restrict__ BT, int ldb,
    void* __restrict__ Cv, int ldc,
    const float* __restrict__ bias, int K) {
  constexpr int BK = 32;
  const int tid = threadIdx.x, wave = tid >> 6, lane = tid & 63;
  const int lr = lane & 15, lq = lane >> 4;
  const int wm = wave >> 1, wn = wave & 1;
  const int m0 = blockIdx.y * 128, n0 = blockIdx.x * 128;
  const int srow = lane >> 2;
  const int scol = (lane & 3) * 8;

  __shared__ alignas(16) bf16 ash[128 * BK];
  __shared__ alignas(16) bf16 bsh[128 * BK];

  f32x4 acc[4][4];
#pragma unroll
  for (int i = 0; i < 4; ++i)
#pragma unroll
    for (int j = 0; j < 4; ++j)
#pragma unroll
      for (int r = 0; r < 4; ++r) acc[i][j][r] = 0.f;

  const int nk = K / BK;
  for (int kt = 0; kt < nk; ++kt) {
    const int k0 = kt * BK;
#pragma unroll
    for (int c = 0; c < 2; ++c) {
      const int rbase = wave * 32 + c * 16;
      gload16(A + (size_t)(m0 + rbase + srow) * lda + k0 + scol, ash + rbase * BK);
      gload16(BT + (size_t)(n0 + rbase + srow) * ldb + k0 + scol, bsh + rbase * BK);
    }
    __syncthreads();
    short8 af[4], bfv[4];
#pragma unroll
    for (int i = 0; i < 4; ++i)
      af[i] = *(const short8*)&ash[(wm * 64 + i * 16 + lr) * BK + lq * 8];
#pragma unroll
    for (int j = 0; j < 4; ++j)
      bfv[j] = *(const short8*)&bsh[(wn * 64 + j * 16 + lr) * BK + lq * 8];
#pragma unroll
    for (int i = 0; i < 4; ++i)
#pragma unroll
      for (int j = 0; j < 4; ++j)
        acc[i][j] = __builtin_amdgcn_mfma_f32_16x16x32_bf16(af[i], bfv[j], acc[i][j], 0, 0, 0);
    __syncthreads();
  }
#pragma unroll
  for (int i = 0; i < 4; ++i) {
    int row0 = m0 + wm * 64 + i * 16 + lq * 4;
#pragma unroll
    for (int j = 0; j < 4; ++j) {
      int col = n0 + wn * 64 + j * 16 + lr;
      float bv = BIAS ? bias[col] : 0.f;
#pragma unroll
      for (int r = 0; r < 4; ++r) {
        float v = acc[i][j][r] + bv;
        if (OUT_BF16) ((bf16*)Cv)[(size_t)(row0 + r) * ldc + col] = f2b(v);
        else          ((float*)Cv)[(size_t)(row0 + r) * ldc + col] = v;
      }
    }
  }
}

// -------------------------------------------------- RoPE + heads + nulls builder
__global__ __launch_bounds__(256) void rope_build_kernel(
    const bf16* __restrict__ qkv, const float* __restrict__ rot,
    const float* __restrict__ nullk, const float* __restrict__ nullv,
    bf16* __restrict__ Q, bf16* __restrict__ Kt, bf16* __restrict__ Vt) {
  const int blk = blockIdx.x;
  const int ic = blk & 63;
  const int h = (blk >> 6) & 15;
  const int b = blk >> 10;
  const int i0 = ic * 32;
  const int tid = threadIdx.x;
  const int bh = b * NH + h;

  __shared__ alignas(16) bf16 sh[33][192];
  __shared__ alignas(16) float cs[33][32], sn[33][32];

  for (int c = 0; c < 4; ++c) {
    int idx = tid + c * 256;
    if (idx < 33 * 24) {
      int row = idx / 24, ch = idx % 24;
      int p = ch >> 3, cc = (ch & 7) * 8;
      int i = i0 - 1 + row;
      if (i >= 0)
        *(short8*)&sh[row][p * 64 + cc] =
            *(const short8*)(qkv + (size_t)(b * SEQ + i) * 3072 + p * 1024 + h * 64 + cc);
    }
  }
  for (int c = 0; c < 5; ++c) {
    int idx = tid + c * 256;
    if (idx < 33 * 32) {
      int row = idx >> 5, d = idx & 31;
      int i = i0 - 1 + row;
      if (i >= 0) {
        float f = rot[i * 32 + d];
        cs[row][d] = cosf(f);
        sn[row][d] = sinf(f);
      }
    }
  }
  __syncthreads();

  auto ropev = [&](int row, int off, int d) -> float {
    float v = b2f(sh[row][off + d]);
    if (d < 32) {
      float c = cs[row][d], s = sn[row][d];
      float v2 = b2f(sh[row][off + (d < 16 ? d + 16 : d - 16)]);
      return d < 16 ? v * c - v2 * s : v * c + v2 * s;
    }
    return v;
  };

  const int dA = tid & 63;
#pragma unroll
  for (int rep = 0; rep < 8; ++rep) {
    int il = rep * 4 + (tid >> 6);
    int row = il + 1;
    int i = i0 + il;
    float qv = ropev(row, 0, dA) * 0.125f;
    float kv = ropev(row, 64, dA);
    Q[((size_t)bh * SEQ + i) * HD + dA] = f2b(qv);
    Kt[((size_t)bh * KPAD + (i + 1)) * HD + dA] = f2b(kv);
  }
  {
    int d = tid >> 2;
    int g0 = (tid & 3) * 8;
    bf16 tmp[8];
#pragma unroll
    for (int u = 0; u < 8; ++u) {
      int j = i0 + g0 + u;
      if (j == 0) tmp[u] = f2b(nullv[h * 64 + d]);
      else        tmp[u] = f2b(ropev(j - i0, 128, d));
    }
    *(short8*)(Vt + ((size_t)bh * HD + d) * KPAD + i0 + g0) = *(short8*)tmp;
  }
  if (i0 == 0 && tid < 64)
    Kt[(size_t)bh * KPAD * HD + tid] = f2b(nullk[h * 64 + tid]);
  if (ic == 63 && tid < 64)
    Vt[((size_t)bh * HD + tid) * KPAD + 2048] = f2b(ropev(32, 128, tid));
}

// ---------------------------------------- pass 1: softmax denominators -> Linv f32
__global__ __launch_bounds__(256) void denom_kernel(
    const bf16* __restrict__ Q, const bf16* __restrict__ Kt, float* __restrict__ Linv) {
  const int bh = blockIdx.x;
  const int i0 = blockIdx.y * 32;
  const int tid = threadIdx.x;
  const int wave = tid >> 6, lane = tid & 63;
  const int lr = lane & 15, lq = lane >> 4;
  const bf16* Qp = Q + (size_t)bh * SEQ * HD;
  const bf16* Kp = Kt + (size_t)bh * KPAD * HD;

  short8 af[2][2];
#pragma unroll
  for (int fi = 0; fi < 2; ++fi)
#pragma unroll
    for (int ks = 0; ks < 2; ++ks)
      af[fi][ks] = *(const short8*)(Qp + (size_t)(i0 + fi * 16 + lr) * HD + ks * 32 + lq * 8);

  const int tmax = (i0 + 32) >> 6;
  float lacc[2][4];
#pragma unroll
  for (int fi = 0; fi < 2; ++fi)
#pragma unroll
    for (int r = 0; r < 4; ++r) lacc[fi][r] = 0.f;

  for (int t = wave; t <= tmax; t += 4) {
    f32x4 s[2][4];
#pragma unroll
    for (int fi = 0; fi < 2; ++fi)
#pragma unroll
      for (int fj = 0; fj < 4; ++fj)
#pragma unroll
        for (int r = 0; r < 4; ++r) s[fi][fj][r] = 0.f;
#pragma unroll
    for (int fj = 0; fj < 4; ++fj) {
      const bf16* kp = Kp + (size_t)(t * 64 + fj * 16 + lr) * HD + lq * 8;
      short8 b0 = *(const short8*)kp;
      short8 b1 = *(const short8*)(kp + 32);
#pragma unroll
      for (int fi = 0; fi < 2; ++fi) {
        s[fi][fj] = __builtin_amdgcn_mfma_f32_16x16x32_bf16(af[fi][0], b0, s[fi][fj], 0, 0, 0);
        s[fi][fj] = __builtin_amdgcn_mfma_f32_16x16x32_bf16(af[fi][1], b1, s[fi][fj], 0, 0, 0);
      }
    }
#pragma unroll
    for (int fi = 0; fi < 2; ++fi)
#pragma unroll
      for (int fj = 0; fj < 4; ++fj)
#pragma unroll
        for (int r = 0; r < 4; ++r) {
          int i = i0 + fi * 16 + lq * 4 + r;
          int j = t * 64 + fj * 16 + lr;
          if (j <= i + 1) lacc[fi][r] += __expf(s[fi][fj][r]);
        }
  }
#pragma unroll
  for (int m = 1; m <= 8; m <<= 1)
#pragma unroll
    for (int fi = 0; fi < 2; ++fi)
#pragma unroll
      for (int r = 0; r < 4; ++r) lacc[fi][r] += __shfl_xor(lacc[fi][r], m, 64);

  __shared__ alignas(16) float lsh[4][32];
  if (lr == 0) {
#pragma unroll
    for (int fi = 0; fi < 2; ++fi)
#pragma unroll
      for (int r = 0; r < 4; ++r) lsh[wave][fi * 16 + lq * 4 + r] = lacc[fi][r];
  }
  __syncthreads();
  if (tid < 32)
    Linv[(size_t)bh * SEQ + i0 + tid] =
        1.f / (lsh[0][tid] + lsh[1][tid] + lsh[2][tid] + lsh[3][tid]);
}

// ---- Path A 2a: per-b QK^T + softmax + talking-heads mix -> Pm[g][i][j] (bf16)
// 512 thr (8 waves x 2 heads). Mix output staged through LDS (XOR-swizzled) and
// written to Pm as coalesced short8. Zero-fills band (tmax, (ic>>1)+1].
__global__ __launch_bounds__(512) void pmix_kernel(
    const bf16* __restrict__ Q, const bf16* __restrict__ Kt,
    const float* __restrict__ Linv, const float* __restrict__ thw,
    bf16* __restrict__ Pm) {
  const int t = blockIdx.x;
  const int ic = blockIdx.y;
  const int i0 = ic * 32;
  const int tid = threadIdx.x, wave = tid >> 6, lane = tid & 63;
  const int lr = lane & 15, lq = lane >> 4;
  const int tmax = (i0 + 32) >> 6;

  short8 zero8;
#pragma unroll
  for (int e = 0; e < 8; ++e) zero8[e] = 0;

  if (t > tmax) {                                  // zero-fill band or skip
    if (t > (ic >> 1) + 1) return;
#pragma unroll
    for (int k = 0; k < 8; ++k) {
      int idx = tid + k * 512;
      int g = idx >> 8, rest = idx & 255;
      int il = rest >> 3, jc = (rest & 7) * 8;
      *(short8*)(Pm + ((size_t)g * SEQ + i0 + il) * KPAD + t * 64 + jc) = zero8;
    }
    return;
  }

  __shared__ alignas(16) bf16 p_sh[2048][16];      // [il*64+jl][h]  64 KB
  __shared__ alignas(16) bf16 p2c[16][512];        // [g][swz c-chunk] 16 KB

  f32x4 fzero;
#pragma unroll
  for (int r = 0; r < 4; ++r) fzero[r] = 0.f;

  short8 wfrag = zero8;                            // W[g=lr][h=lq*8+e], k>=16 zero
  if (lq < 2) {
    bf16 tmp[8];
#pragma unroll
    for (int e = 0; e < 8; ++e) tmp[e] = f2b(thw[lr * 16 + lq * 8 + e]);
    wfrag = *(short8*)tmp;
  }

#pragma unroll
  for (int hh = 0; hh < 2; ++hh) {
    const int h = wave * 2 + hh;
    const bf16* Qp = Q + ((size_t)h * SEQ + i0) * HD;
    const bf16* Kp = Kt + ((size_t)h * KPAD + t * 64) * HD;
    short8 qf[2][2];
#pragma unroll
    for (int fi = 0; fi < 2; ++fi)
#pragma unroll
      for (int ks = 0; ks < 2; ++ks)
        qf[fi][ks] = *(const short8*)(Qp + (size_t)(fi * 16 + lr) * HD + ks * 32 + lq * 8);
    float linv[2][4];
#pragma unroll
    for (int fi = 0; fi < 2; ++fi)
#pragma unroll
      for (int r = 0; r < 4; ++r)
        linv[fi][r] = Linv[(size_t)h * SEQ + i0 + fi * 16 + lq * 4 + r];

    f32x4 s[2][4];
#pragma unroll
    for (int fi = 0; fi < 2; ++fi)
#pragma unroll
      for (int fj = 0; fj < 4; ++fj) s[fi][fj] = fzero;
#pragma unroll
    for (int fj = 0; fj < 4; ++fj) {
      const bf16* kp = Kp + (size_t)(fj * 16 + lr) * HD + lq * 8;
      short8 b0 = *(const short8*)kp;
      short8 b1 = *(const short8*)(kp + 32);
#pragma unroll
      for (int fi = 0; fi < 2; ++fi) {
        s[fi][fj] = __builtin_amdgcn_mfma_f32_16x16x32_bf16(qf[fi][0], b0, s[fi][fj], 0, 0, 0);
        s[fi][fj] = __builtin_amdgcn_mfma_f32_16x16x32_bf16(qf[fi][1], b1, s[fi][fj], 0, 0, 0);
      }
    }
#pragma unroll
    for (int fi = 0; fi < 2; ++fi)
#pragma unroll
      for (int fj = 0; fj < 4; ++fj)
#pragma unroll
        for (int r = 0; r < 4; ++r) {
          int il = fi * 16 + lq * 4 + r;
          int jl = fj * 16 + lr;
          int i = i0 + il, j = t * 64 + jl;
          float p = (j <= i + 1) ? __expf(s[fi][fj][r]) * linv[fi][r] : 0.f;
          p_sh[il * 64 + jl][h] = f2b(p);
        }
  }
  __syncthreads();

  // mix + staged coalesced write, 4 chunks of 512 columns (8 il-rows each)
  for (int ch = 0; ch < 4; ++ch) {
#pragma unroll
    for (int q = 0; q < 4; ++q) {
      const int cl = (wave * 4 + q) * 16 + lr;     // 0..511 chunk-local
      const int c  = ch * 512 + cl;
      short8 bfrag = zero8;
      if (lq < 2) bfrag = *(const short8*)&p_sh[c][lq * 8];
      f32x4 d = __builtin_amdgcn_mfma_f32_16x16x32_bf16(wfrag, bfrag, fzero, 0, 0, 0);
      const int es = cl ^ (((cl >> 6) & 7) << 3);  // involution swizzle
#pragma unroll
      for (int r = 0; r < 4; ++r)
        p2c[lq * 4 + r][es] = f2b(d[r]);
    }
    __syncthreads();
#pragma unroll
    for (int it = 0; it < 2; ++it) {
      const int u = tid + it * 512;                // 16g x 8il x 8(jc/8)
      const int g = u >> 6, rest = u & 63;
      const int il = rest >> 3, jc = (rest & 7) * 8;
      const int es = (il * 64 + jc) ^ (il << 3);
      short8 v = *(const short8*)&p2c[g][es];
      *(short8*)(Pm + ((size_t)g * SEQ + i0 + ch * 8 + il) * KPAD + t * 64 + jc) = v;
    }
    __syncthreads();
  }
}

// ---- Path A 2b: per-b oh[i, g*64+d] = sum_j Pm[g,i,j] * Vt[g,d,j], K-lim m0+65
__global__ __launch_bounds__(256) void pv64_kernel(
    const bf16* __restrict__ Pm, const bf16* __restrict__ Vt, bf16* __restrict__ oh) {
  const int g = blockIdx.x;
  const int m0 = blockIdx.y * 64;
  const int tid = threadIdx.x, w = tid >> 6, lane = tid & 63;
  const int lr = lane & 15, lq = lane >> 4;
  const bf16* A  = Pm + (size_t)g * SEQ * KPAD;
  const bf16* BT = Vt + (size_t)g * HD * KPAD;

  __shared__ alignas(16) bf16 ash[64][40];
  __shared__ alignas(16) bf16 bsh[64][40];

  f32x4 acc[4];
#pragma unroll
  for (int j = 0; j < 4; ++j)
#pragma unroll
    for (int r = 0; r < 4; ++r) acc[j][r] = 0.f;

  const int nk = m0 / 32 + 3;                       // covers K = m0 + 96 > m0+65
  for (int kt = 0; kt < nk; ++kt) {
    const int k0 = kt * 32;
    *(short8*)&ash[tid >> 2][(tid & 3) * 8] =
        *(const short8*)(A + (size_t)(m0 + (tid >> 2)) * KPAD + k0 + (tid & 3) * 8);
    *(short8*)&bsh[tid >> 2][(tid & 3) * 8] =
        *(const short8*)(BT + (size_t)(tid >> 2) * KPAD + k0 + (tid & 3) * 8);
    __syncthreads();
    short8 af = *(const short8*)&ash[w * 16 + lr][lq * 8];
#pragma unroll
    for (int j = 0; j < 4; ++j) {
      short8 bfv = *(const short8*)&bsh[j * 16 + lr][lq * 8];
      acc[j] = __builtin_amdgcn_mfma_f32_16x16x32_bf16(af, bfv, acc[j], 0, 0, 0);
    }
    __syncthreads();
  }
#pragma unroll
  for (int j = 0; j < 4; ++j)
#pragma unroll
    for (int r = 0; r < 4; ++r)
      oh[(size_t)(m0 + w * 16 + lq * 4 + r) * DM + g * 64 + j * 16 + lr] = f2b(acc[j][r]);
}

// ---- Path B fallback: r6 fused2 (measured 181us) --------------------------------
__global__ __launch_bounds__(512) void fused2_kernel(
    const bf16* __restrict__ Q, const bf16* __restrict__ Kt, const bf16* __restrict__ Vt,
    const float* __restrict__ Linv, const float* __restrict__ thw,
    float* __restrict__ ohf) {
  const int pairIdx = blockIdx.x >> 2;
  const int b  = (blockIdx.x >> 1) & 1;
  const int jh = blockIdx.x & 1;
  const int tid = threadIdx.x;
  const int w = tid >> 6, lane = tid & 63;
  const int lr = lane & 15, lq = lane >> 4;

  __shared__ alignas(16) bf16 p_sh[1024 * 24];
  __shared__ alignas(16) bf16 p2[16 * 1032];

  short8 zero8;
#pragma unroll
  for (int e = 0; e < 8; ++e) zero8[e] = 0;
  f32x4 fzero;
#pragma unroll
  for (int r = 0; r < 4; ++r) fzero[r] = 0.f;

  short8 wfrag = zero8;
  if (lq < 2) {
    bf16 tmp[8];
#pragma unroll
    for (int e = 0; e < 8; ++e) tmp[e] = f2b(thw[lr * 16 + lq * 8 + e]);
    wfrag = *(short8*)tmp;
  }

#pragma unroll
  for (int sel = 0; sel < 2; ++sel) {
    const int ic = sel ? 127 - pairIdx : pairIdx;
    const int i0 = ic * 16;
    const int n = ((i0 + 16) >> 6) + 1;
    const int half = (n + 1) >> 1;
    const int t0 = jh ? half : 0;
    const int t1 = jh ? n : half;

    short8 qf[2][2];
    float linv[2][4];
    const bf16* Vp[2];
    const bf16* Kp[2];
#pragma unroll
    for (int hh = 0; hh < 2; ++hh) {
      const int h = w + hh * 8;
      const int bh = b * NH + h;
      const bf16* Qp = Q + ((size_t)bh * SEQ + i0) * HD;
#pragma unroll
      for (int ks = 0; ks < 2; ++ks)
        qf[hh][ks] = *(const short8*)(Qp + (size_t)lr * HD + ks * 32 + lq * 8);
#pragma unroll
      for (int r = 0; r < 4; ++r)
        linv[hh][r] = Linv[(size_t)bh * SEQ + i0 + lq * 4 + r];
      Kp[hh] = Kt + (size_t)bh * KPAD * HD;
      Vp[hh] = Vt + (size_t)bh * HD * KPAD;
    }

    f32x4 oacc[2][4];
#pragma unroll
    for (int hh = 0; hh < 2; ++hh)
#pragma unroll
      for (int fn = 0; fn < 4; ++fn) oacc[hh][fn] = fzero;

    for (int t = t0; t < t1; ++t) {
#pragma unroll
      for (int hh = 0; hh < 2; ++hh) {
        const int h = w + hh * 8;
        f32x4 s[4];
#pragma unroll
        for (int fj = 0; fj < 4; ++fj) s[fj] = fzero;
#pragma unroll
        for (int fj = 0; fj < 4; ++fj) {
          const bf16* kp = Kp[hh] + (size_t)(t * 64 + fj * 16 + lr) * HD + lq * 8;
          short8 b0 = *(const short8*)kp;
          short8 b1 = *(const short8*)(kp + 32);
          s[fj] = __builtin_amdgcn_mfma_f32_16x16x32_bf16(qf[hh][0], b0, s[fj], 0, 0, 0);
          s[fj] = __builtin_amdgcn_mfma_f32_16x16x32_bf16(qf[hh][1], b1, s[fj], 0, 0, 0);
        }
#pragma unroll
        for (int fj = 0; fj < 4; ++fj)
#pragma unroll
          for (int r = 0; r < 4; ++r) {
            int il = lq * 4 + r;
            int jl = fj * 16 + lr;
            int i = i0 + il, j = t * 64 + jl;
            float p = (j <= i + 1) ? __expf(s[fj][r]) * linv[hh][r] : 0.f;
            p_sh[(il * 64 + jl) * 24 + h] = f2b(p);
          }
      }
      __syncthreads();
#pragma unroll
      for (int q = 0; q < 8; ++q) {
        const int c = (w * 8 + q) * 16 + lr;
        short8 bfrag = zero8;
        if (lq < 2) bfrag = *(const short8*)&p_sh[c * 24 + lq * 8];
        f32x4 d = __builtin_amdgcn_mfma_f32_16x16x32_bf16(wfrag, bfrag, fzero, 0, 0, 0);
        const int sc = c ^ (((c >> 6) & 7) << 3);
#pragma unroll
        for (int r = 0; r < 4; ++r)
          p2[(lq * 4 + r) * 1032 + sc] = f2b(d[r]);
      }
      __syncthreads();
#pragma unroll
      for (int hh = 0; hh < 2; ++hh) {
        const int h = w + hh * 8;
        short8 pa[2];
#pragma unroll
        for (int ks = 0; ks < 2; ++ks) {
          const int c = lr * 64 + ks * 32 + lq * 8;
          const int sc = c ^ (((c >> 6) & 7) << 3);
          pa[ks] = *(const short8*)&p2[h * 1032 + sc];
        }
#pragma unroll
        for (int fn = 0; fn < 4; ++fn) {
          const bf16* vp = Vp[hh] + (size_t)(fn * 16 + lr) * KPAD + t * 64 + lq * 8;
          short8 v0 = *(const short8*)vp;
          short8 v1 = *(const short8*)(vp + 32);
          oacc[hh][fn] = __builtin_amdgcn_mfma_f32_16x16x32_bf16(pa[0], v0, oacc[hh][fn], 0, 0, 0);
          oacc[hh][fn] = __builtin_amdgcn_mfma_f32_16x16x32_bf16(pa[1], v1, oacc[hh][fn], 0, 0, 0);
        }
      }
    }
#pragma unroll
    for (int hh = 0; hh < 2; ++hh) {
      const int h = w + hh * 8;
#pragma unroll
      for (int fn = 0; fn < 4; ++fn)
#pragma unroll
        for (int r = 0; r < 4; ++r)
          atomicAdd(ohf + (size_t)(b * SEQ + i0 + lq * 4 + r) * DM + h * 64 + fn * 16 + lr,
                    oacc[hh][fn][r]);
    }
    __syncthreads();
  }
}

// ------------------------------------------------------------------- launcher
extern "C" void kernel_launch(void* const* d_in, const int* in_sizes, int n_in,
                              void* d_out, int out_size, void* d_ws, size_t ws_size,
                              hipStream_t stream) {
  const float* x     = (const float*)d_in[0];
  const float* rot   = (const float*)d_in[2];
  const float* nullk = (const float*)d_in[3];
  const float* nullv = (const float*)d_in[4];
  const float* thw   = (const float*)d_in[5];
  const float* wq    = (const float*)d_in[6];
  const float* wkv   = (const float*)d_in[7];
  const float* wout  = (const float*)d_in[8];
  const float* bout  = (const float*)d_in[9];
  float* out = (float*)d_out;

  char* ws = (char*)d_ws;
  size_t off = 0;
  auto alloc = [&](size_t bytes) { char* p = ws + off; off += (bytes + 255) & ~(size_t)255; return p; };
  bf16* x_bf    = (bf16*)alloc((size_t)BB * SEQ * DM * 2);        // 8.4 MB
  bf16* wqkv_t  = (bf16*)alloc((size_t)3072 * 1024 * 2);          // 6.3 MB
  bf16* wout_t  = (bf16*)alloc((size_t)1024 * 1024 * 2);          // 2.1 MB
  bf16* Qb      = (bf16*)alloc((size_t)BB * NH * SEQ * HD * 2);   // 8.4 MB
  bf16* Kt      = (bf16*)alloc((size_t)BB * NH * KPAD * HD * 2);  // 8.7 MB
  bf16* Vt      = (bf16*)alloc((size_t)BB * NH * HD * KPAD * 2);  // 8.7 MB
  float* Linv   = (float*)alloc((size_t)BB * NH * SEQ * 4);       // 0.26 MB
  bf16* oh      = (bf16*)alloc((size_t)BB * SEQ * DM * 2);        // 8.4 MB
  // shared region: qkv_bf (25.2 MB, dead after rope) overlapped with Pm (138.4 MB)
  const size_t shared_off = off;
  bf16* qkv_bf = (bf16*)(ws + shared_off);
  bf16* Pm     = (bf16*)(ws + shared_off);
  const size_t PM_BYTES = (size_t)NH * SEQ * KPAD * 2;            // per-b: 138.4 MB
  const bool pathA = (shared_off + PM_BYTES) <= ws_size;          // needs ~189.6 MB
  float* ohf = (float*)qkv_bf;                                    // Path B accumulator

  cast_x_kernel<<<(BB * SEQ * DM / 4 + 255) / 256, 256, 0, stream>>>(x, x_bf, BB * SEQ * DM / 4);
  transpose_cast_kernel<<<dim3(1024 / 32, 1024 / 32), 256, 0, stream>>>(wq, wqkv_t, 1024, 1024);
  transpose_cast_kernel<<<dim3(2048 / 32, 1024 / 32), 256, 0, stream>>>(wkv, wqkv_t + (size_t)1024 * 1024, 2048, 1024);
  transpose_cast_kernel<<<dim3(1024 / 32, 1024 / 32), 256, 0, stream>>>(wout, wout_t, 1024, 1024);

  gemm_lds_kernel<true, false>
      <<<dim3(3072 / 128, 4096 / 128), 256, 0, stream>>>(
          x_bf, 1024, wqkv_t, 1024, qkv_bf, 3072, nullptr, 1024);

  rope_build_kernel<<<BB * NH * (SEQ / 32), 256, 0, stream>>>(qkv_bf, rot, nullk, nullv, Qb, Kt, Vt);

  denom_kernel<<<dim3(BB * NH, SEQ / 32), 256, 0, stream>>>(Qb, Kt, Linv);

  if (pathA) {
    for (int b = 0; b < BB; ++b) {
      pmix_kernel<<<dim3(33, 64), 512, 0, stream>>>(
          Qb + (size_t)b * NH * SEQ * HD,
          Kt + (size_t)b * NH * KPAD * HD,
          Linv + (size_t)b * NH * SEQ, thw, Pm);
      pv64_kernel<<<dim3(16, 32), 256, 0, stream>>>(
          Pm, Vt + (size_t)b * NH * HD * KPAD, oh + (size_t)b * SEQ * DM);
    }
  } else {
    zero_kernel<<<(BB * SEQ * DM / 4 + 255) / 256, 256, 0, stream>>>(ohf, BB * SEQ * DM / 4);
    fused2_kernel<<<256, 512, 0, stream>>>(Qb, Kt, Vt, Linv, thw, ohf);
    cast_o_kernel<<<(BB * SEQ * DM / 4 + 255) / 256, 256, 0, stream>>>(ohf, oh, BB * SEQ * DM / 4);
  }

  gemm_lds_kernel<false, true>
      <<<dim3(1024 / 128, 4096 / 128), 256, 0, stream>>>(
          oh, 1024, wout_t, 1024, out, 1024, bout, 1024);
}